// Round 5
// baseline (57.818 us; speedup 1.0000x reference)
//
#include <hip/hip_runtime.h>

// PopulationAttention: out = (Q K^T / sqrt(64)) @ (V * x)
// No softmax => associativity: out = Q @ M, M = K^T @ (V*x) / 8  (64x64 per head)
// B=4, H=16, N=2048, D=64  -> BH=64 batched heads.
//
// 2 kernels, coherence via kernel boundary only (NO device-scope fences —
// R2 showed per-block __threadfence costs 4x on CDNA4's non-coherent XCD L2s).
// Stage A streams K/V from global with wave-private row slices (zero LDS in
// the hot loop); stage B folds the 8-partial reduction into its prologue.

#define BH 64
#define NROWS 2048
#define DIM 64
#define NCH 8  // chunks per head in stage A (hardcoded; ws needs 8 MB)

// ---- Stage A: partial[bh][ch] = sum_{m in slice} K[m]^T (V[m]*x[m]) ----
// grid (NCH, BH), 256 threads. Each wave owns a private contiguous 64-row
// slice; 8x8 per-thread register tile over the 64x64 output; K/V stream
// from global (8-lane broadcast float4s, every byte read once device-wide).
// Fixed-order cross-wave LDS reduce tail -> deterministic.
__global__ __launch_bounds__(256, 2) void popattn_kv(
    const float* __restrict__ K, const float* __restrict__ V,
    const float* __restrict__ x, float* __restrict__ partial) {
  const int ch = blockIdx.x;
  const int bh = blockIdx.y;
  const float* Kp = K + (size_t)bh * (NROWS * DIM);
  const float* Vp = V + (size_t)bh * (NROWS * DIM);
  const float* xp = x + (size_t)(bh >> 4) * NROWS;  // x is [B,1,N,1], b = bh/16

  const int t = threadIdx.x;
  const int wv = t >> 6;          // wave id 0..3
  const int l = t & 63;
  const int ti = (l >> 3) << 3;   // 8x8 tile row base (K column block)
  const int tj = (l & 7) << 3;    // 8x8 tile col base (V column block)

  float acc[8][8];
#pragma unroll
  for (int i = 0; i < 8; ++i)
#pragma unroll
    for (int j = 0; j < 8; ++j) acc[i][j] = 0.f;

  const int mstart = ch * (NROWS / NCH) + wv * (NROWS / NCH / 4);  // wave-private
#pragma unroll 2
  for (int m = mstart; m < mstart + (NROWS / NCH / 4); ++m) {
    const float4 k0 = *(const float4*)(Kp + (size_t)m * DIM + ti);
    const float4 k1 = *(const float4*)(Kp + (size_t)m * DIM + ti + 4);
    const float4 v0 = *(const float4*)(Vp + (size_t)m * DIM + tj);
    const float4 v1 = *(const float4*)(Vp + (size_t)m * DIM + tj + 4);
    const float xv = xp[m];
    const float kk[8] = {k0.x, k0.y, k0.z, k0.w, k1.x, k1.y, k1.z, k1.w};
    float vw[8] = {v0.x, v0.y, v0.z, v0.w, v1.x, v1.y, v1.z, v1.w};
#pragma unroll
    for (int j = 0; j < 8; ++j) vw[j] *= xv;
#pragma unroll
    for (int i = 0; i < 8; ++i)
#pragma unroll
      for (int j = 0; j < 8; ++j) acc[i][j] += kk[i] * vw[j];
  }

  // ---- cross-wave reduce in LDS, fixed order s=0..3 (deterministic) ----
  __shared__ float smem[DIM * DIM];  // 16 KB
#pragma unroll 1
  for (int s = 0; s < 4; ++s) {
    if (wv == s) {
#pragma unroll
      for (int ii = 0; ii < 8; ++ii) {
        float* dst = &smem[(ti + ii) * DIM + tj];
        if (s == 0) {
          float4 o;
          o.x = acc[ii][0]; o.y = acc[ii][1]; o.z = acc[ii][2]; o.w = acc[ii][3];
          *(float4*)dst = o;
          o.x = acc[ii][4]; o.y = acc[ii][5]; o.z = acc[ii][6]; o.w = acc[ii][7];
          *(float4*)(dst + 4) = o;
        } else {
          float4 a = *(float4*)dst;
          a.x += acc[ii][0]; a.y += acc[ii][1]; a.z += acc[ii][2]; a.w += acc[ii][3];
          *(float4*)dst = a;
          a = *(float4*)(dst + 4);
          a.x += acc[ii][4]; a.y += acc[ii][5]; a.z += acc[ii][6]; a.w += acc[ii][7];
          *(float4*)(dst + 4) = a;
        }
      }
    }
    __syncthreads();
  }

  float* Pp = partial + ((size_t)bh * NCH + ch) * (DIM * DIM);
#pragma unroll
  for (int i = 0; i < 4; ++i) {
    const int idx = (t + 256 * i) * 4;
    *(float4*)(Pp + idx) = *(const float4*)&smem[idx];
  }
}

// ---- Stage B: out[bh] = Q[bh] @ M[bh], M reduced from partials in prologue ----
// grid (NROWS/256, BH), 256 threads; per-thread 8x8 tile (rows r+32*rr).
__global__ __launch_bounds__(256, 2) void popattn_qm(
    const float* __restrict__ Q, const float* __restrict__ partial,
    float* __restrict__ out) {
  const int ch = blockIdx.x;  // 0..7
  const int bh = blockIdx.y;
  const int row0 = ch * 256;
  const float* Qp = Q + (size_t)bh * (NROWS * DIM) + (size_t)row0 * DIM;
  float* Op = out + (size_t)bh * (NROWS * DIM) + (size_t)row0 * DIM;

  __shared__ float sM[DIM * DIM];  // 16 KB

  const int t = threadIdx.x;
  {
    // fixed-order reduction of the NCH partials, fold scale 1/8
    const float* Pp = partial + (size_t)bh * NCH * (DIM * DIM);
#pragma unroll
    for (int e = 0; e < 4; ++e) {
      const int off = e * 1024 + t * 4;
      float sx = 0.f, sy = 0.f, sz = 0.f, sw = 0.f;
#pragma unroll
      for (int c = 0; c < NCH; ++c) {
        const float4 p = *(const float4*)(Pp + (size_t)c * (DIM * DIM) + off);
        sx += p.x; sy += p.y; sz += p.z; sw += p.w;
      }
      float4 o;
      o.x = sx * 0.125f; o.y = sy * 0.125f; o.z = sz * 0.125f; o.w = sw * 0.125f;
      *(float4*)&sM[off] = o;
    }
  }
  __syncthreads();

  const int r = t >> 3;         // rows r + 32*rr, rr = 0..7
  const int c8 = (t & 7) * 8;   // cols c8..c8+7

  float acc[8][8];
#pragma unroll
  for (int rr = 0; rr < 8; ++rr)
#pragma unroll
    for (int jj = 0; jj < 8; ++jj) acc[rr][jj] = 0.f;

#pragma unroll 2
  for (int kg = 0; kg < 16; ++kg) {
    float4 qv[8];
#pragma unroll
    for (int rr = 0; rr < 8; ++rr)
      qv[rr] = *(const float4*)(Qp + (size_t)(r + 32 * rr) * DIM + kg * 4);
#pragma unroll
    for (int dk = 0; dk < 4; ++dk) {
      const int k = kg * 4 + dk;
      const float4 m0 = *(const float4*)&sM[k * DIM + c8];
      const float4 m1 = *(const float4*)&sM[k * DIM + c8 + 4];
      const float mm[8] = {m0.x, m0.y, m0.z, m0.w, m1.x, m1.y, m1.z, m1.w};
#pragma unroll
      for (int rr = 0; rr < 8; ++rr) {
        const float q = (dk == 0) ? qv[rr].x : (dk == 1) ? qv[rr].y
                       : (dk == 2) ? qv[rr].z : qv[rr].w;
#pragma unroll
        for (int jj = 0; jj < 8; ++jj) acc[rr][jj] += q * mm[jj];
      }
    }
  }

#pragma unroll
  for (int rr = 0; rr < 8; ++rr) {
    float4 o;
    o.x = acc[rr][0]; o.y = acc[rr][1]; o.z = acc[rr][2]; o.w = acc[rr][3];
    *(float4*)(Op + (size_t)(r + 32 * rr) * DIM + c8) = o;
    o.x = acc[rr][4]; o.y = acc[rr][5]; o.z = acc[rr][6]; o.w = acc[rr][7];
    *(float4*)(Op + (size_t)(r + 32 * rr) * DIM + c8 + 4) = o;
  }
}

extern "C" void kernel_launch(void* const* d_in, const int* in_sizes, int n_in,
                              void* d_out, int out_size, void* d_ws, size_t ws_size,
                              hipStream_t stream) {
  const float* Q = (const float*)d_in[0];
  const float* K = (const float*)d_in[1];
  const float* V = (const float*)d_in[2];
  const float* x = (const float*)d_in[3];
  float* out = (float*)d_out;
  float* partial = (float*)d_ws;  // BH * NCH * 64*64 floats = 8 MB

  dim3 blk(256);
  popattn_kv<<<dim3(NCH, BH), blk, 0, stream>>>(K, V, x, partial);
  popattn_qm<<<dim3(NROWS / 256, BH), blk, 0, stream>>>(Q, partial, out);
}